// Round 5
// baseline (440.003 us; speedup 1.0000x reference)
//
#include <hip/hip_runtime.h>
#include <math.h>

// Problem constants (from reference setup_inputs)
#define CDIM 5
constexpr int B_ = 16;
constexpr int C_ = 256;
constexpr int HW_ = 128 * 128;     // 16384 elements per (b,c) plane
constexpr float MOM = 0.1f;

using f32x4 = __attribute__((ext_vector_type(4))) float;

// ---------------------------------------------------------------------------
// Tiny kernel: zero the per-channel rendezvous counters (must be zero at the
// start of every call; harness does not re-poison ws between replays).
// ---------------------------------------------------------------------------
__global__ __launch_bounds__(256) void cin_zero(int* __restrict__ cnt) {
    cnt[threadIdx.x] = 0;
}

// ---------------------------------------------------------------------------
// Fused kernel: one block per (b,c) plane.  Blocks of the same channel c are
// CONSECUTIVE in blockIdx (blockIdx = c*16 + b) so each 16-block rendezvous
// group is dispatched together.
//
//  1. load own 64 KB plane into registers (16 x f32x4 per thread, NT loads)
//  2. block-reduce -> mean/std; publish via agent-scope atomics; bump
//     per-channel counter (release)
//  3. spin (thread 0) until counter == 16; then pull the channel's 16
//     mean/std pairs into LDS
//  4. block-uniform batch-scan + c_trg reduction -> scale/shift
//  5. write out = im*scale + shift from registers (NT stores)
//
// im is read ONCE (536 MB total traffic vs 804 MB for the 2-pass version).
// Residency: __launch_bounds__(256,4) caps VGPR at 128 -> >=4 blocks/CU ->
// >=1024 co-resident blocks >> group size 16, so the oldest incomplete
// group always completes (stream-K-style forward progress).
// ---------------------------------------------------------------------------
__global__ __launch_bounds__(256, 4) void cin_fused(
        const float* __restrict__ im,
        const float* __restrict__ running_mean,
        const float* __restrict__ running_std,
        const int* __restrict__ c_trg,
        const int* __restrict__ c_org,
        float* __restrict__ ws_mean,
        float* __restrict__ ws_std,
        int* __restrict__ ws_cnt,
        float* __restrict__ out) {
    const int c = blockIdx.x >> 4;      // channel 0..255
    const int b = blockIdx.x & 15;      // batch   0..15
    const int plane = b * C_ + c;
    const int t = threadIdx.x;

    // ---- 1. load plane into registers (NT: zero reuse by design) ----
    const f32x4* p4 = (const f32x4*)(im + (size_t)plane * HW_);
    f32x4 v[16];
    #pragma unroll
    for (int it = 0; it < 16; ++it)
        v[it] = __builtin_nontemporal_load(&p4[it * 256 + t]);

    float sum = 0.f, sumsq = 0.f;
    #pragma unroll
    for (int it = 0; it < 16; ++it) {
        sum   += v[it].x + v[it].y + v[it].z + v[it].w;
        sumsq += v[it].x * v[it].x + v[it].y * v[it].y
               + v[it].z * v[it].z + v[it].w * v[it].w;
    }

    // ---- 2. block reduce + publish ----
    #pragma unroll
    for (int off = 32; off > 0; off >>= 1) {
        sum   += __shfl_down(sum, off, 64);
        sumsq += __shfl_down(sumsq, off, 64);
    }
    __shared__ float s_sum[4], s_sq[4];
    const int wave = t >> 6;
    if ((t & 63) == 0) { s_sum[wave] = sum; s_sq[wave] = sumsq; }
    __syncthreads();

    if (t == 0) {
        float s = s_sum[0] + s_sum[1] + s_sum[2] + s_sum[3];
        float q = s_sq[0] + s_sq[1] + s_sq[2] + s_sq[3];
        float mean = s / (float)HW_;
        float var  = fmaxf(q - s * mean, 0.f) / (float)(HW_ - 1);
        float sd   = sqrtf(var);
        __hip_atomic_store(&ws_mean[plane], mean, __ATOMIC_RELAXED,
                           __HIP_MEMORY_SCOPE_AGENT);
        __hip_atomic_store(&ws_std[plane], sd, __ATOMIC_RELAXED,
                           __HIP_MEMORY_SCOPE_AGENT);
        __hip_atomic_fetch_add(&ws_cnt[c], 1, __ATOMIC_RELEASE,
                               __HIP_MEMORY_SCOPE_AGENT);
        // ---- 3. rendezvous: wait for all 16 planes of this channel ----
        while (__hip_atomic_load(&ws_cnt[c], __ATOMIC_ACQUIRE,
                                 __HIP_MEMORY_SCOPE_AGENT) < B_)
            __builtin_amdgcn_s_sleep(2);
    }
    __syncthreads();

    // pull the channel's stats into LDS (agent-scope loads bypass stale L1/L2)
    __shared__ float s_mn[B_], s_sd[B_];
    if (t < B_) {
        s_mn[t] = __hip_atomic_load(&ws_mean[t * C_ + c], __ATOMIC_RELAXED,
                                    __HIP_MEMORY_SCOPE_AGENT);
    } else if (t < 2 * B_) {
        s_sd[t - B_] = __hip_atomic_load(&ws_std[(t - B_) * C_ + c],
                                         __ATOMIC_RELAXED,
                                         __HIP_MEMORY_SCOPE_AGENT);
    }
    __syncthreads();

    // ---- 4. block-uniform batch-scan for channel c ----
    float rm[2 * CDIM], rs[2 * CDIM];
    #pragma unroll
    for (int r = 0; r < 2 * CDIM; ++r) {
        rm[r] = running_mean[r * C_ + c];
        rs[r] = running_std [r * C_ + c];
    }
    for (int n = 0; n < B_; ++n) {
        const float mn = s_mn[n];
        const float sd = s_sd[n];
        int bits[CDIM];
        #pragma unroll
        for (int k = 0; k < CDIM; ++k) bits[k] = c_org[n * CDIM + k];
        #pragma unroll
        for (int r = 0; r < 2 * CDIM; ++r) {
            const int k = (r < CDIM) ? r : r - CDIM;
            const bool msk = (r < CDIM) ? (bits[k] != 0) : (bits[k] == 0);
            if (msk) {
                rs[r] = rs[r] * (1.f - MOM) + sd * MOM;
                rm[r] = rm[r] * (1.f - MOM) + mn * MOM;
            }
        }
    }

    // target stats for batch b -> scale/shift
    float tm = 0.f, ts = 0.f, cnt = 0.f;
    #pragma unroll
    for (int r = 0; r < 2 * CDIM; ++r) {
        const int k = (r < CDIM) ? r : r - CDIM;
        const int bit = c_trg[b * CDIM + k];
        const bool sel = (r < CDIM) ? (bit != 0) : (bit == 0);
        if (sel) { cnt += 1.f; tm += rm[r]; ts += rs[r]; }
    }
    tm /= cnt;
    ts /= cnt;
    const float mean  = s_mn[b];
    const float std   = s_sd[b];
    const float scale = ts / std;
    const float shift = tm - mean * scale;

    // ---- 5. normalize from registers, NT stores ----
    f32x4* o4 = (f32x4*)(out + (size_t)plane * HW_);
    #pragma unroll
    for (int it = 0; it < 16; ++it) {
        f32x4 r;
        r.x = fmaf(v[it].x, scale, shift);
        r.y = fmaf(v[it].y, scale, shift);
        r.z = fmaf(v[it].z, scale, shift);
        r.w = fmaf(v[it].w, scale, shift);
        __builtin_nontemporal_store(r, &o4[it * 256 + t]);
    }
}

// ---------------------------------------------------------------------------
extern "C" void kernel_launch(void* const* d_in, const int* in_sizes, int n_in,
                              void* d_out, int out_size, void* d_ws, size_t ws_size,
                              hipStream_t stream) {
    const float* im           = (const float*)d_in[0];
    const float* running_mean = (const float*)d_in[1];
    const float* running_std  = (const float*)d_in[2];
    const int*   c_trg        = (const int*)d_in[3];
    const int*   c_org        = (const int*)d_in[4];
    float* out = (float*)d_out;

    // Workspace layout (floats): mean[4096] | std[4096] | cnt[256 ints]
    float* ws      = (float*)d_ws;
    float* ws_mean = ws;
    float* ws_std  = ws + B_ * C_;
    int*   ws_cnt  = (int*)(ws + 2 * B_ * C_);

    cin_zero<<<1, C_, 0, stream>>>(ws_cnt);
    cin_fused<<<B_ * C_, 256, 0, stream>>>(im, running_mean, running_std,
                                           c_trg, c_org, ws_mean, ws_std,
                                           ws_cnt, out);
}

// Round 6
// 126.842 us; speedup vs baseline: 3.4689x; 3.4689x over previous
//
#include <hip/hip_runtime.h>
#include <math.h>

// Problem constants (from reference setup_inputs)
#define CDIM 5
constexpr int B_ = 16;
constexpr int C_ = 256;
constexpr int HW_ = 128 * 128;     // 16384 elements per (b,c) plane
constexpr float MOM = 0.1f;

using f32x4 = __attribute__((ext_vector_type(4))) float;

// ---------------------------------------------------------------------------
// Kernel 1: per-plane mean / std.  One block per (b,c) plane.
// 256 threads x 16 float4 loads = 16384 floats.
// ---------------------------------------------------------------------------
__global__ __launch_bounds__(256) void cin_stats(const float* __restrict__ im,
                                                 float* __restrict__ ws_mean,
                                                 float* __restrict__ ws_std) {
    const int plane = blockIdx.x;                // b*C + c
    const f32x4* p4 = (const f32x4*)(im + (size_t)plane * HW_);
    const int t = threadIdx.x;

    float sum = 0.f, sumsq = 0.f;
    #pragma unroll
    for (int it = 0; it < 16; ++it) {
        f32x4 v = p4[it * 256 + t];
        sum   += v.x + v.y + v.z + v.w;
        sumsq += v.x * v.x + v.y * v.y + v.z * v.z + v.w * v.w;
    }

    // wave64 butterfly reduce
    #pragma unroll
    for (int off = 32; off > 0; off >>= 1) {
        sum   += __shfl_down(sum, off, 64);
        sumsq += __shfl_down(sumsq, off, 64);
    }

    __shared__ float s_sum[4], s_sq[4];
    const int wave = t >> 6;
    if ((t & 63) == 0) { s_sum[wave] = sum; s_sq[wave] = sumsq; }
    __syncthreads();

    if (t == 0) {
        float s = s_sum[0] + s_sum[1] + s_sum[2] + s_sum[3];
        float q = s_sq[0] + s_sq[1] + s_sq[2] + s_sq[3];
        float mean = s / (float)HW_;
        // var = (sumsq - N*mean^2)/(N-1) = (q - s*mean)/(N-1)
        float var = fmaxf(q - s * mean, 0.f) / (float)(HW_ - 1);
        ws_mean[plane] = mean;
        ws_std[plane]  = sqrtf(var);
    }
}

// ---------------------------------------------------------------------------
// Kernel 2: normalize.  One block per plane.  Each block redundantly computes
// the batch-scan for its channel (block-uniform scalar work: ~130 uniform
// L2-hot loads + ~320 FMAs, pipelined across the 16 blocks/CU — negligible),
// derives scale/shift, then streams: out = im*scale + shift.
// Stores are NONTEMPORAL (write-only stream; avoid L1/L2 churn).
// ---------------------------------------------------------------------------
__global__ __launch_bounds__(256) void cin_norm(const float* __restrict__ im,
                                                const float* __restrict__ running_mean,
                                                const float* __restrict__ running_std,
                                                const int* __restrict__ c_trg,
                                                const int* __restrict__ c_org,
                                                const float* __restrict__ ws_mean,
                                                const float* __restrict__ ws_std,
                                                float* __restrict__ out) {
    const int plane = blockIdx.x;
    const int b = plane >> 8;           // plane / C_
    const int c = plane & (C_ - 1);     // plane % C_

    // ---- inline batch-scan for channel c (block-uniform) ----
    float rm[2 * CDIM], rs[2 * CDIM];
    #pragma unroll
    for (int r = 0; r < 2 * CDIM; ++r) {
        rm[r] = running_mean[r * C_ + c];
        rs[r] = running_std [r * C_ + c];
    }
    for (int n = 0; n < B_; ++n) {
        const float mn = ws_mean[n * C_ + c];
        const float sd = ws_std [n * C_ + c];
        int bits[CDIM];
        #pragma unroll
        for (int k = 0; k < CDIM; ++k) bits[k] = c_org[n * CDIM + k];
        #pragma unroll
        for (int r = 0; r < 2 * CDIM; ++r) {
            const int k = (r < CDIM) ? r : r - CDIM;
            const bool msk = (r < CDIM) ? (bits[k] != 0) : (bits[k] == 0);
            if (msk) {
                rs[r] = rs[r] * (1.f - MOM) + sd * MOM;
                rm[r] = rm[r] * (1.f - MOM) + mn * MOM;
            }
        }
    }

    // ---- target stats for batch b -> scale/shift ----
    float tm = 0.f, ts = 0.f, cnt = 0.f;
    #pragma unroll
    for (int r = 0; r < 2 * CDIM; ++r) {
        const int k = (r < CDIM) ? r : r - CDIM;
        const int bit = c_trg[b * CDIM + k];
        const bool sel = (r < CDIM) ? (bit != 0) : (bit == 0);
        if (sel) { cnt += 1.f; tm += rm[r]; ts += rs[r]; }
    }
    tm /= cnt;
    ts /= cnt;
    const float mean  = ws_mean[plane];
    const float std   = ws_std [plane];
    const float scale = ts / std;
    const float shift = tm - mean * scale;

    // ---- streaming normalize ----
    const f32x4* p4 = (const f32x4*)(im + (size_t)plane * HW_);
    f32x4*       o4 = (f32x4*)(out + (size_t)plane * HW_);
    const int t = threadIdx.x;

    #pragma unroll
    for (int it = 0; it < 16; ++it) {
        f32x4 v = p4[it * 256 + t];
        f32x4 r;
        r.x = fmaf(v.x, scale, shift);
        r.y = fmaf(v.y, scale, shift);
        r.z = fmaf(v.z, scale, shift);
        r.w = fmaf(v.w, scale, shift);
        __builtin_nontemporal_store(r, &o4[it * 256 + t]);
    }
}

// ---------------------------------------------------------------------------
extern "C" void kernel_launch(void* const* d_in, const int* in_sizes, int n_in,
                              void* d_out, int out_size, void* d_ws, size_t ws_size,
                              hipStream_t stream) {
    const float* im           = (const float*)d_in[0];
    const float* running_mean = (const float*)d_in[1];
    const float* running_std  = (const float*)d_in[2];
    const int*   c_trg        = (const int*)d_in[3];
    const int*   c_org        = (const int*)d_in[4];
    float* out = (float*)d_out;

    // Workspace layout (floats): mean[4096] | std[4096]
    float* ws      = (float*)d_ws;
    float* ws_mean = ws;
    float* ws_std  = ws + B_ * C_;

    const int planes = B_ * C_;   // 4096

    cin_stats<<<planes, 256, 0, stream>>>(im, ws_mean, ws_std);
    cin_norm <<<planes, 256, 0, stream>>>(im, running_mean, running_std,
                                          c_trg, c_org, ws_mean, ws_std, out);
}